// Round 1
// baseline (1036.893 us; speedup 1.0000x reference)
//
#include <hip/hip_runtime.h>
#include <stdint.h>

#define NN 8192
#define DH 512
#define NH 4
#define LOG2E 1.4426950408889634f

typedef __attribute__((ext_vector_type(8))) short short8;
typedef __attribute__((ext_vector_type(4))) float f32x4;

__device__ __forceinline__ unsigned short f2bf(float f) {
    unsigned int u = __float_as_uint(f);
    unsigned int r = (u + 0x7fffu + ((u >> 16) & 1u)) >> 16;
    return (unsigned short)r;
}
__device__ __forceinline__ float bf2f(unsigned short s) {
    return __uint_as_float(((unsigned int)s) << 16);
}

__device__ __forceinline__ void global_to_lds16(const void* g, void* l) {
    __builtin_amdgcn_global_load_lds(
        (const __attribute__((address_space(1))) unsigned int*)g,
        (__attribute__((address_space(3))) unsigned int*)l, 16, 0, 0);
}

// ---------------- kernel 0a: h fp32 -> bf16 ----------------
__global__ void k_convert_h(const float* __restrict__ hf, unsigned short* __restrict__ hb) {
    const int idx = (blockIdx.x * 256 + threadIdx.x) * 8;
    const float4 f0 = *(const float4*)(hf + idx);
    const float4 f1 = *(const float4*)(hf + idx + 4);
    uint4 o;
    o.x = (unsigned)f2bf(f0.x) | ((unsigned)f2bf(f0.y) << 16);
    o.y = (unsigned)f2bf(f0.z) | ((unsigned)f2bf(f0.w) << 16);
    o.z = (unsigned)f2bf(f1.x) | ((unsigned)f2bf(f1.y) << 16);
    o.w = (unsigned)f2bf(f1.z) | ((unsigned)f2bf(f1.w) << 16);
    *(uint4*)(hb + idx) = o;
}

// ---------------- kernel 0b: W (512x2048) fp32 -> Wt (2048x512) bf16 ----------------
__global__ void k_transpose_W(const float* __restrict__ W, unsigned short* __restrict__ Wt) {
    __shared__ float t[32][33];
    const int tx = threadIdx.x & 31, ty = threadIdx.x >> 5;  // 256 threads: ty 0..7
    const int p0 = blockIdx.x * 32, k0 = blockIdx.y * 32;
#pragma unroll
    for (int r = 0; r < 4; r++)
        t[ty + r * 8][tx] = W[(k0 + ty + r * 8) * 2048 + p0 + tx];
    __syncthreads();
#pragma unroll
    for (int r = 0; r < 4; r++)
        Wt[(size_t)(p0 + ty + r * 8) * 512 + k0 + tx] = f2bf(t[tx][ty + r * 8]);
}

// ---------------- kernel 1: vt (2048 x 8192) = Wt (2048x512) @ hb^T ----------------
// vt[h*512+d][n] = ht[n][h*512+d]  (bf16). m97-style 128x128x64 tile, 4 waves.
__global__ __launch_bounds__(256, 3) void k_gemm(const unsigned short* __restrict__ Wt,
                                                 const unsigned short* __restrict__ hb,
                                                 unsigned short* __restrict__ vt) {
    __shared__ alignas(16) char smem[32768];  // A tile 16KB | B tile 16KB
    const int tid = threadIdx.x;
    const int w = tid >> 6, lane = tid & 63;
    const int lr = lane & 15, lc = lane >> 4;
    const int pBase = blockIdx.y * 128, nBase = blockIdx.x * 128;
    f32x4 acc[4][4] = {};
    const int wr = (w >> 1) * 64, wc = (w & 1) * 64;
    for (int kb = 0; kb < 8; kb++) {
        const int k0 = kb * 64;
#pragma unroll
        for (int it = 0; it < 4; it++) {
            const int o = it * 4096 + w * 1024 + lane * 16;
            const int row = o >> 7;
            const int koff = (o & 127) >> 1;
            global_to_lds16(Wt + (size_t)(pBase + row) * 512 + k0 + koff,
                            smem + it * 4096 + w * 1024);
            global_to_lds16(hb + (size_t)(nBase + row) * 512 + k0 + koff,
                            smem + 16384 + it * 4096 + w * 1024);
        }
        __syncthreads();
#pragma unroll
        for (int kk = 0; kk < 2; kk++) {
            short8 a[4], b[4];
#pragma unroll
            for (int m = 0; m < 4; m++)
                a[m] = *(const short8*)(smem + (wr + m * 16 + lr) * 128 + kk * 64 + lc * 16);
#pragma unroll
            for (int n = 0; n < 4; n++)
                b[n] = *(const short8*)(smem + 16384 + (wc + n * 16 + lr) * 128 + kk * 64 + lc * 16);
#pragma unroll
            for (int m = 0; m < 4; m++)
#pragma unroll
                for (int n = 0; n < 4; n++)
                    acc[m][n] = __builtin_amdgcn_mfma_f32_16x16x32_bf16(a[m], b[n], acc[m][n], 0, 0, 0);
        }
        __syncthreads();
    }
#pragma unroll
    for (int m = 0; m < 4; m++)
#pragma unroll
        for (int n = 0; n < 4; n++)
#pragma unroll
            for (int q = 0; q < 4; q++) {
                const int p = pBase + wr + m * 16 + lc * 4 + q;
                const int ncol = nBase + wc + n * 16 + lr;
                vt[(size_t)p * NN + ncol] = f2bf(acc[m][n][q]);
            }
}

// ---------------- kernel 2: srcL/dstL[h][n] = log2e * sum_d vt[h*512+d][n]*a_{src/dst}[h][d] ----
__global__ void k_srcdst(const unsigned short* __restrict__ vt, const float* __restrict__ a,
                         float* __restrict__ srcL, float* __restrict__ dstL) {
    const int n = blockIdx.x * 256 + threadIdx.x;
    const int h = blockIdx.y;
    float s = 0.f, t = 0.f;
    for (int d = 0; d < 512; d++) {
        const float v = bf2f(vt[(size_t)(h * 512 + d) * NN + n]);
        s += v * a[h * 1024 + d];
        t += v * a[h * 1024 + 512 + d];
    }
    srcL[h * NN + n] = s * LOG2E;
    dstL[h * NN + n] = t * LOG2E;
}

// ---------------- kernel 3: fused masked-softmax attention + PV + mean ----------------
// grid: 256 blocks = (i-block 128 rows) x (head); 8 waves.
// Per 32-j step: wave w scores rows w*16..+16 (A-frag layout), P shared via LDS;
// PV: wave (ih=w>>2, dq=w&3) computes rows ih*64..+64 x d dq*128..+128.
#define V_OFF 0
#define P_OFF 32768
#define D_OFF 40960
__global__ __launch_bounds__(512, 2) void k_flash(const float* __restrict__ adj,
                                                  const unsigned short* __restrict__ vt,
                                                  const float* __restrict__ srcL,
                                                  const float* __restrict__ dstL,
                                                  float* __restrict__ out) {
    __shared__ alignas(16) char smem[41472];  // V 32KB | P 8KB | denom 512B
    const int tid = threadIdx.x;
    const int w = tid >> 6, lane = tid & 63;
    const int lr = lane & 15, lc = lane >> 4;
    const int h = blockIdx.x & 3;
    const int i0 = (int)(blockIdx.x >> 2) * 128;
    const int ih = w >> 2, dq = w & 3;
    float* denom = (float*)(smem + D_OFF);

    const int srow = i0 + w * 16 + lr;  // this lane's scoring row (global i)
    const float srcv = srcL[h * NN + srow];
    const float* __restrict__ adjrow = adj + (size_t)srow * NN;
    const float* __restrict__ dstLh = dstL + h * NN;
    const unsigned short* __restrict__ vth = vt + (size_t)(h * 512) * NN;
    float dsum = 0.f;
    f32x4 acc[4][8] = {};

#pragma unroll 1
    for (int jb = 0; jb < NN / 32; jb++) {
        const int j0 = jb * 32;
        // --- stage V tile: d in [0,512), j in [j0,j0+32), paired-row XOR layout ---
#pragma unroll
        for (int it = 0; it < 4; it++) {
            const int o = it * 8192 + w * 1024 + lane * 16;
            const int row = o >> 7;                  // d-pair row
            const int z = ((o >> 4) & 7) ^ (row & 7);
            const int d = (row << 1) | (z >> 2);
            const int j = j0 + ((z & 3) << 3);
            global_to_lds16(vth + (size_t)d * NN + j, smem + V_OFF + it * 8192 + w * 1024);
        }
        // --- scores: 8 elements/lane, p = exp2(leaky(srcL+dstL) + adj) ---
        const int jc8 = j0 + lc * 8;
        const float4 aj0 = *(const float4*)(adjrow + jc8);
        const float4 aj1 = *(const float4*)(adjrow + jc8 + 4);
        const float4 dl0 = *(const float4*)(dstLh + jc8);
        const float4 dl1 = *(const float4*)(dstLh + jc8 + 4);
        const float padj[8] = {aj0.x, aj0.y, aj0.z, aj0.w, aj1.x, aj1.y, aj1.z, aj1.w};
        const float pdst[8] = {dl0.x, dl0.y, dl0.z, dl0.w, dl1.x, dl1.y, dl1.z, dl1.w};
        short8 pfrag;
#pragma unroll
        for (int q = 0; q < 8; q++) {
            const float x = srcv + pdst[q];
            const float l2 = fmaxf(x, 0.01f * x);
            const float p = exp2f(l2 + padj[q]);
            dsum += p;
            pfrag[q] = (short)f2bf(p);
        }
        {   // write P (row r, j-chunk lc), paired-row XOR layout
            const int r = w * 16 + lr;
            const int sl = (((r & 1) << 2) | lc) ^ ((r >> 1) & 7);
            *(short8*)(smem + P_OFF + (r >> 1) * 128 + (sl << 4)) = pfrag;
        }
        __syncthreads();  // P visible + V staged (vmcnt drained at barrier)
        // --- PV ---
        short8 afr[4];
#pragma unroll
        for (int t = 0; t < 4; t++) {
            const int rr = ih * 64 + t * 16 + lr;
            const int sl = (((rr & 1) << 2) | lc) ^ ((rr >> 1) & 7);
            afr[t] = *(const short8*)(smem + P_OFF + (rr >> 1) * 128 + (sl << 4));
        }
#pragma unroll
        for (int s = 0; s < 8; s++) {
            const int d = dq * 128 + s * 16 + lr;
            const int sl = (((d & 1) << 2) | lc) ^ ((d >> 1) & 7);
            const short8 bfr = *(const short8*)(smem + V_OFF + (d >> 1) * 128 + (sl << 4));
#pragma unroll
            for (int t = 0; t < 4; t++)
                acc[t][s] = __builtin_amdgcn_mfma_f32_16x16x32_bf16(afr[t], bfr, acc[t][s], 0, 0, 0);
        }
        __syncthreads();  // all reads done before next stage overwrites V/P
    }
    // --- denominators: reduce 4 lane-partials per row ---
    dsum += __shfl_xor(dsum, 16, 64);
    dsum += __shfl_xor(dsum, 32, 64);
    if (lane < 16) denom[w * 16 + lane] = dsum;
    __syncthreads();
    // --- epilogue: out[i][d] += 0.25 * acc / denom ---
#pragma unroll
    for (int t = 0; t < 4; t++) {
        const int rl = ih * 64 + t * 16 + lc * 4;
#pragma unroll
        for (int q = 0; q < 4; q++) {
            const float inv = 0.25f / denom[rl + q];
            float* orow = out + (size_t)(i0 + rl + q) * 512;
#pragma unroll
            for (int s = 0; s < 8; s++) {
                const int d = dq * 128 + s * 16 + lr;
                __hip_atomic_fetch_add(orow + d, acc[t][s][q] * inv,
                                       __ATOMIC_RELAXED, __HIP_MEMORY_SCOPE_AGENT);
            }
        }
    }
}

extern "C" void kernel_launch(void* const* d_in, const int* in_sizes, int n_in,
                              void* d_out, int out_size, void* d_ws, size_t ws_size,
                              hipStream_t stream) {
    const float* h = (const float*)d_in[0];
    const float* adj = (const float*)d_in[1];
    const float* W = (const float*)d_in[2];
    const float* a = (const float*)d_in[3];
    float* out = (float*)d_out;
    char* ws = (char*)d_ws;
    unsigned short* hb = (unsigned short*)ws;                                  // 8 MB
    unsigned short* Wt = (unsigned short*)(ws + 8388608);                      // 2 MB
    unsigned short* vt = (unsigned short*)(ws + 8388608 + 2097152);            // 32 MB
    float* srcL = (float*)(ws + 8388608 + 2097152 + 33554432);                 // 128 KB
    float* dstL = srcL + NH * NN;                                              // 128 KB

    hipMemsetAsync(d_out, 0, (size_t)out_size * sizeof(float), stream);
    k_convert_h<<<2048, 256, 0, stream>>>(h, hb);
    k_transpose_W<<<dim3(64, 16), 256, 0, stream>>>(W, Wt);
    k_gemm<<<dim3(64, 16), 256, 0, stream>>>(Wt, hb, vt);
    k_srcdst<<<dim3(32, NH), 256, 0, stream>>>(vt, a, srcL, dstL);
    k_flash<<<256, 512, 0, stream>>>(adj, vt, srcL, dstL, out);
}

// Round 2
// 874.803 us; speedup vs baseline: 1.1853x; 1.1853x over previous
//
#include <hip/hip_runtime.h>
#include <stdint.h>

#define NN 8192
#define DH 512
#define NH 4
#define LOG2E 1.4426950408889634f

typedef __attribute__((ext_vector_type(8))) short short8;
typedef __attribute__((ext_vector_type(4))) float f32x4;

__device__ __forceinline__ unsigned short f2bf(float f) {
    unsigned int u = __float_as_uint(f);
    unsigned int r = (u + 0x7fffu + ((u >> 16) & 1u)) >> 16;
    return (unsigned short)r;
}
__device__ __forceinline__ float bf2f(unsigned short s) {
    return __uint_as_float(((unsigned int)s) << 16);
}

__device__ __forceinline__ void global_to_lds16(const void* g, void* l) {
    __builtin_amdgcn_global_load_lds(
        (const __attribute__((address_space(1))) unsigned int*)g,
        (__attribute__((address_space(3))) unsigned int*)l, 16, 0, 0);
}

// ---------------- kernel 0a: h fp32 -> bf16 ----------------
__global__ void k_convert_h(const float* __restrict__ hf, unsigned short* __restrict__ hb) {
    const int idx = (blockIdx.x * 256 + threadIdx.x) * 8;
    const float4 f0 = *(const float4*)(hf + idx);
    const float4 f1 = *(const float4*)(hf + idx + 4);
    uint4 o;
    o.x = (unsigned)f2bf(f0.x) | ((unsigned)f2bf(f0.y) << 16);
    o.y = (unsigned)f2bf(f0.z) | ((unsigned)f2bf(f0.w) << 16);
    o.z = (unsigned)f2bf(f1.x) | ((unsigned)f2bf(f1.y) << 16);
    o.w = (unsigned)f2bf(f1.z) | ((unsigned)f2bf(f1.w) << 16);
    *(uint4*)(hb + idx) = o;
}

// ---------------- kernel 0b: W (512x2048) fp32 -> Wt (2048x512) bf16 ----------------
__global__ void k_transpose_W(const float* __restrict__ W, unsigned short* __restrict__ Wt) {
    __shared__ float t[32][33];
    const int tx = threadIdx.x & 31, ty = threadIdx.x >> 5;
    const int p0 = blockIdx.x * 32, k0 = blockIdx.y * 32;
#pragma unroll
    for (int r = 0; r < 4; r++)
        t[ty + r * 8][tx] = W[(k0 + ty + r * 8) * 2048 + p0 + tx];
    __syncthreads();
#pragma unroll
    for (int r = 0; r < 4; r++)
        Wt[(size_t)(p0 + ty + r * 8) * 512 + k0 + tx] = f2bf(t[tx][ty + r * 8]);
}

// ---------------- kernel 1: vt (2048 x 8192) = Wt (2048x512) @ hb^T ----------------
__global__ __launch_bounds__(256, 3) void k_gemm(const unsigned short* __restrict__ Wt,
                                                 const unsigned short* __restrict__ hb,
                                                 unsigned short* __restrict__ vt) {
    __shared__ alignas(16) char smem[32768];
    const int tid = threadIdx.x;
    const int w = tid >> 6, lane = tid & 63;
    const int lr = lane & 15, lc = lane >> 4;
    const int pBase = blockIdx.y * 128, nBase = blockIdx.x * 128;
    f32x4 acc[4][4] = {};
    const int wr = (w >> 1) * 64, wc = (w & 1) * 64;
    for (int kb = 0; kb < 8; kb++) {
        const int k0 = kb * 64;
#pragma unroll
        for (int it = 0; it < 4; it++) {
            const int o = it * 4096 + w * 1024 + lane * 16;
            const int row = o >> 7;
            const int koff = (o & 127) >> 1;
            global_to_lds16(Wt + (size_t)(pBase + row) * 512 + k0 + koff,
                            smem + it * 4096 + w * 1024);
            global_to_lds16(hb + (size_t)(nBase + row) * 512 + k0 + koff,
                            smem + 16384 + it * 4096 + w * 1024);
        }
        __syncthreads();
#pragma unroll
        for (int kk = 0; kk < 2; kk++) {
            short8 a[4], b[4];
#pragma unroll
            for (int m = 0; m < 4; m++)
                a[m] = *(const short8*)(smem + (wr + m * 16 + lr) * 128 + kk * 64 + lc * 16);
#pragma unroll
            for (int n = 0; n < 4; n++)
                b[n] = *(const short8*)(smem + 16384 + (wc + n * 16 + lr) * 128 + kk * 64 + lc * 16);
#pragma unroll
            for (int m = 0; m < 4; m++)
#pragma unroll
                for (int n = 0; n < 4; n++)
                    acc[m][n] = __builtin_amdgcn_mfma_f32_16x16x32_bf16(a[m], b[n], acc[m][n], 0, 0, 0);
        }
        __syncthreads();
    }
#pragma unroll
    for (int m = 0; m < 4; m++)
#pragma unroll
        for (int n = 0; n < 4; n++)
#pragma unroll
            for (int q = 0; q < 4; q++) {
                const int p = pBase + wr + m * 16 + lc * 4 + q;
                const int ncol = nBase + wc + n * 16 + lr;
                vt[(size_t)p * NN + ncol] = f2bf(acc[m][n][q]);
            }
}

// ---------------- kernel 2: srcL/dstL partials (d-split x8, atomic accumulate) ----------
__global__ void k_srcdst(const unsigned short* __restrict__ vt, const float* __restrict__ a,
                         float* __restrict__ srcL, float* __restrict__ dstL) {
    const int n = blockIdx.x * 256 + threadIdx.x;
    const int h = blockIdx.y;
    const int d0 = blockIdx.z * 64;
    float s = 0.f, t = 0.f;
#pragma unroll 4
    for (int d = d0; d < d0 + 64; d++) {
        const float v = bf2f(vt[(size_t)(h * 512 + d) * NN + n]);
        s += v * a[h * 1024 + d];
        t += v * a[h * 1024 + 512 + d];
    }
    __hip_atomic_fetch_add(&srcL[h * NN + n], s * LOG2E, __ATOMIC_RELAXED, __HIP_MEMORY_SCOPE_AGENT);
    __hip_atomic_fetch_add(&dstL[h * NN + n], t * LOG2E, __ATOMIC_RELAXED, __HIP_MEMORY_SCOPE_AGENT);
}

// ---------------- kernel 3: fused masked-softmax attention + PV + mean ----------------
// 256 blocks = (i-block 128 rows) x head; 8 waves; double-buffered V/P, 1 barrier/iter.
#define VB(b) (smem + (b) * 32768)
#define PB(b) (smem + 65536 + (b) * 8192)
#define D_OFF 81920
#define NJT (NN / 32)
__global__ __launch_bounds__(512, 2) void k_flash(const float* __restrict__ adj,
                                                  const unsigned short* __restrict__ vt,
                                                  const float* __restrict__ srcL,
                                                  const float* __restrict__ dstL,
                                                  float* __restrict__ out) {
    __shared__ alignas(16) char smem[82432];  // V 2x32KB | P 2x8KB | denom 512B
    const int tid = threadIdx.x;
    const int w = tid >> 6, lane = tid & 63;
    const int lr = lane & 15, lc = lane >> 4;
    const int h = blockIdx.x & 3;
    const int i0 = (int)(blockIdx.x >> 2) * 128;
    const int ih = w >> 2, dq = w & 3;
    float* denom = (float*)(smem + D_OFF);

    const int srow = i0 + w * 16 + lr;
    const float srcv = srcL[h * NN + srow];
    const float* __restrict__ adjrow = adj + (size_t)srow * NN;
    const float* __restrict__ dstLh = dstL + h * NN;
    const unsigned short* __restrict__ vth = vt + (size_t)(h * 512) * NN;
    float dsum = 0.f;
    f32x4 acc[4][8] = {};

    // P write slot for this lane (row r = w*16+lr, j-chunk lc), paired-row XOR layout
    const int prow = w * 16 + lr;
    const int psl = (((prow & 1) << 2) | lc) ^ ((prow >> 1) & 7);
    const int poff = (prow >> 1) * 128 + (psl << 4);

#define STAGE(J0, BUF)                                                                   \
    {                                                                                    \
        _Pragma("unroll") for (int it = 0; it < 4; it++) {                               \
            const int o = it * 8192 + w * 1024 + lane * 16;                              \
            const int row = o >> 7;                                                      \
            const int z = ((o >> 4) & 7) ^ (row & 7);                                    \
            const int d = (row << 1) | (z >> 2);                                         \
            const int j = (J0) + ((z & 3) << 3);                                         \
            global_to_lds16(vth + (size_t)d * NN + j, VB(BUF) + it * 8192 + w * 1024);   \
        }                                                                                \
    }

#define LOADROW(J0)                                                                      \
    {                                                                                    \
        const int jc8 = (J0) + lc * 8;                                                   \
        aj0 = *(const float4*)(adjrow + jc8);                                            \
        aj1 = *(const float4*)(adjrow + jc8 + 4);                                        \
        dl0 = *(const float4*)(dstLh + jc8);                                             \
        dl1 = *(const float4*)(dstLh + jc8 + 4);                                         \
    }

#define SCORE()                                                                          \
    {                                                                                    \
        const float padj[8] = {aj0.x, aj0.y, aj0.z, aj0.w, aj1.x, aj1.y, aj1.z, aj1.w};  \
        const float pdst[8] = {dl0.x, dl0.y, dl0.z, dl0.w, dl1.x, dl1.y, dl1.z, dl1.w};  \
        _Pragma("unroll") for (int q = 0; q < 8; q++) {                                  \
            const float x = srcv + pdst[q];                                              \
            const float l2 = fmaxf(x, 0.01f * x);                                        \
            const float p = exp2f(l2 + padj[q]);                                         \
            dsum += p;                                                                   \
            pfrag[q] = (short)f2bf(p);                                                   \
        }                                                                                \
    }

#define PV(BUF)                                                                          \
    {                                                                                    \
        const char* vb = VB(BUF);                                                        \
        const char* pb = PB(BUF);                                                        \
        short8 afr[4];                                                                   \
        _Pragma("unroll") for (int t = 0; t < 4; t++) {                                  \
            const int rr = ih * 64 + t * 16 + lr;                                        \
            const int sl = (((rr & 1) << 2) | lc) ^ ((rr >> 1) & 7);                     \
            afr[t] = *(const short8*)(pb + (rr >> 1) * 128 + (sl << 4));                 \
        }                                                                                \
        __builtin_amdgcn_s_setprio(1);                                                   \
        _Pragma("unroll") for (int s = 0; s < 8; s++) {                                  \
            const int d = dq * 128 + s * 16 + lr;                                        \
            const int sl = (((d & 1) << 2) | lc) ^ ((d >> 1) & 7);                       \
            const short8 bfr = *(const short8*)(vb + (d >> 1) * 128 + (sl << 4));        \
            _Pragma("unroll") for (int t = 0; t < 4; t++)                                \
                acc[t][s] = __builtin_amdgcn_mfma_f32_16x16x32_bf16(afr[t], bfr,         \
                                                                    acc[t][s], 0, 0, 0); \
        }                                                                                \
        __builtin_amdgcn_s_setprio(0);                                                   \
    }

    float4 aj0, aj1, dl0, dl1;
    short8 pfrag;
    // ---- prologue: tile 0 ----
    LOADROW(0);
    STAGE(0, 0);
    SCORE();
    *(short8*)(PB(0) + poff) = pfrag;
    __syncthreads();
    // ---- steady state: compute tile jb, prefetch tile jb+1 ----
#pragma unroll 1
    for (int jb = 0; jb < NJT - 1; jb++) {
        const int cur = jb & 1, nxt = cur ^ 1;
        LOADROW((jb + 1) * 32);
        STAGE((jb + 1) * 32, nxt);
        PV(cur);
        SCORE();
        *(short8*)(PB(nxt) + poff) = pfrag;
        __syncthreads();
    }
    PV((NJT - 1) & 1);

    // --- denominators: reduce 4 lane-partials per row ---
    dsum += __shfl_xor(dsum, 16, 64);
    dsum += __shfl_xor(dsum, 32, 64);
    if (lane < 16) denom[w * 16 + lane] = dsum;
    __syncthreads();
    // --- epilogue: out[i][d] += 0.25 * acc / denom ---
#pragma unroll
    for (int t = 0; t < 4; t++) {
        const int rl = ih * 64 + t * 16 + lc * 4;
#pragma unroll
        for (int q = 0; q < 4; q++) {
            const float inv = 0.25f / denom[rl + q];
            float* orow = out + (size_t)(i0 + rl + q) * 512;
#pragma unroll
            for (int s = 0; s < 8; s++) {
                const int d = dq * 128 + s * 16 + lr;
                __hip_atomic_fetch_add(orow + d, acc[t][s][q] * inv,
                                       __ATOMIC_RELAXED, __HIP_MEMORY_SCOPE_AGENT);
            }
        }
    }
}

extern "C" void kernel_launch(void* const* d_in, const int* in_sizes, int n_in,
                              void* d_out, int out_size, void* d_ws, size_t ws_size,
                              hipStream_t stream) {
    const float* h = (const float*)d_in[0];
    const float* adj = (const float*)d_in[1];
    const float* W = (const float*)d_in[2];
    const float* a = (const float*)d_in[3];
    float* out = (float*)d_out;
    char* ws = (char*)d_ws;
    unsigned short* hb = (unsigned short*)ws;                                  // 8 MB
    unsigned short* Wt = (unsigned short*)(ws + 8388608);                      // 2 MB
    unsigned short* vt = (unsigned short*)(ws + 8388608 + 2097152);            // 32 MB
    float* srcL = (float*)(ws + 8388608 + 2097152 + 33554432);                 // 128 KB
    float* dstL = srcL + NH * NN;                                              // 128 KB

    hipMemsetAsync(d_out, 0, (size_t)out_size * sizeof(float), stream);
    hipMemsetAsync(srcL, 0, 2 * NH * NN * sizeof(float), stream);
    k_convert_h<<<2048, 256, 0, stream>>>(h, hb);
    k_transpose_W<<<dim3(64, 16), 256, 0, stream>>>(W, Wt);
    k_gemm<<<dim3(64, 16), 256, 0, stream>>>(Wt, hb, vt);
    k_srcdst<<<dim3(32, NH, 8), 256, 0, stream>>>(vt, a, srcL, dstL);
    k_flash<<<256, 512, 0, stream>>>(adj, vt, srcL, dstL, out);
}

// Round 3
// 808.761 us; speedup vs baseline: 1.2821x; 1.0817x over previous
//
#include <hip/hip_runtime.h>
#include <stdint.h>

#define NN 8192
#define DH 512
#define NH 4
#define LOG2E 1.4426950408889634f

typedef __attribute__((ext_vector_type(8))) short short8;
typedef __attribute__((ext_vector_type(4))) float f32x4;

__device__ __forceinline__ unsigned short f2bf(float f) {
    unsigned int u = __float_as_uint(f);
    unsigned int r = (u + 0x7fffu + ((u >> 16) & 1u)) >> 16;
    return (unsigned short)r;
}
__device__ __forceinline__ float bf2f(unsigned short s) {
    return __uint_as_float(((unsigned int)s) << 16);
}

__device__ __forceinline__ void global_to_lds16(const void* g, void* l) {
    __builtin_amdgcn_global_load_lds(
        (const __attribute__((address_space(1))) unsigned int*)g,
        (__attribute__((address_space(3))) unsigned int*)l, 16, 0, 0);
}

// ---------------- kernel 0a: h fp32 -> bf16 ----------------
__global__ void k_convert_h(const float* __restrict__ hf, unsigned short* __restrict__ hb) {
    const int idx = (blockIdx.x * 256 + threadIdx.x) * 8;
    const float4 f0 = *(const float4*)(hf + idx);
    const float4 f1 = *(const float4*)(hf + idx + 4);
    uint4 o;
    o.x = (unsigned)f2bf(f0.x) | ((unsigned)f2bf(f0.y) << 16);
    o.y = (unsigned)f2bf(f0.z) | ((unsigned)f2bf(f0.w) << 16);
    o.z = (unsigned)f2bf(f1.x) | ((unsigned)f2bf(f1.y) << 16);
    o.w = (unsigned)f2bf(f1.z) | ((unsigned)f2bf(f1.w) << 16);
    *(uint4*)(hb + idx) = o;
}

// ---------------- kernel 0b: W (512x2048) fp32 -> Wt (2048x512) bf16 ----------------
__global__ void k_transpose_W(const float* __restrict__ W, unsigned short* __restrict__ Wt) {
    __shared__ float t[32][33];
    const int tx = threadIdx.x & 31, ty = threadIdx.x >> 5;
    const int p0 = blockIdx.x * 32, k0 = blockIdx.y * 32;
#pragma unroll
    for (int r = 0; r < 4; r++)
        t[ty + r * 8][tx] = W[(k0 + ty + r * 8) * 2048 + p0 + tx];
    __syncthreads();
#pragma unroll
    for (int r = 0; r < 4; r++)
        Wt[(size_t)(p0 + ty + r * 8) * 512 + k0 + tx] = f2bf(t[tx][ty + r * 8]);
}

// ---------------- kernel 1: vt (2048 x 8192) = Wt (2048x512) @ hb^T ----------------
__global__ __launch_bounds__(256, 3) void k_gemm(const unsigned short* __restrict__ Wt,
                                                 const unsigned short* __restrict__ hb,
                                                 unsigned short* __restrict__ vt) {
    __shared__ alignas(16) char smem[32768];
    const int tid = threadIdx.x;
    const int w = tid >> 6, lane = tid & 63;
    const int lr = lane & 15, lc = lane >> 4;
    const int pBase = blockIdx.y * 128, nBase = blockIdx.x * 128;
    f32x4 acc[4][4] = {};
    const int wr = (w >> 1) * 64, wc = (w & 1) * 64;
    for (int kb = 0; kb < 8; kb++) {
        const int k0 = kb * 64;
#pragma unroll
        for (int it = 0; it < 4; it++) {
            const int o = it * 4096 + w * 1024 + lane * 16;
            const int row = o >> 7;
            const int koff = (o & 127) >> 1;
            global_to_lds16(Wt + (size_t)(pBase + row) * 512 + k0 + koff,
                            smem + it * 4096 + w * 1024);
            global_to_lds16(hb + (size_t)(nBase + row) * 512 + k0 + koff,
                            smem + 16384 + it * 4096 + w * 1024);
        }
        __syncthreads();
#pragma unroll
        for (int kk = 0; kk < 2; kk++) {
            short8 a[4], b[4];
#pragma unroll
            for (int m = 0; m < 4; m++)
                a[m] = *(const short8*)(smem + (wr + m * 16 + lr) * 128 + kk * 64 + lc * 16);
#pragma unroll
            for (int n = 0; n < 4; n++)
                b[n] = *(const short8*)(smem + 16384 + (wc + n * 16 + lr) * 128 + kk * 64 + lc * 16);
#pragma unroll
            for (int m = 0; m < 4; m++)
#pragma unroll
                for (int n = 0; n < 4; n++)
                    acc[m][n] = __builtin_amdgcn_mfma_f32_16x16x32_bf16(a[m], b[n], acc[m][n], 0, 0, 0);
        }
        __syncthreads();
    }
#pragma unroll
    for (int m = 0; m < 4; m++)
#pragma unroll
        for (int n = 0; n < 4; n++)
#pragma unroll
            for (int q = 0; q < 4; q++) {
                const int p = pBase + wr + m * 16 + lc * 4 + q;
                const int ncol = nBase + wc + n * 16 + lr;
                vt[(size_t)p * NN + ncol] = f2bf(acc[m][n][q]);
            }
}

// ---------------- kernel 2: srcL/dstL partials (d-split x8, atomic accumulate) ----------
__global__ void k_srcdst(const unsigned short* __restrict__ vt, const float* __restrict__ a,
                         float* __restrict__ srcL, float* __restrict__ dstL) {
    const int n = blockIdx.x * 256 + threadIdx.x;
    const int h = blockIdx.y;
    const int d0 = blockIdx.z * 64;
    float s = 0.f, t = 0.f;
#pragma unroll 4
    for (int d = d0; d < d0 + 64; d++) {
        const float v = bf2f(vt[(size_t)(h * 512 + d) * NN + n]);
        s += v * a[h * 1024 + d];
        t += v * a[h * 1024 + 512 + d];
    }
    __hip_atomic_fetch_add(&srcL[h * NN + n], s * LOG2E, __ATOMIC_RELAXED, __HIP_MEMORY_SCOPE_AGENT);
    __hip_atomic_fetch_add(&dstL[h * NN + n], t * LOG2E, __ATOMIC_RELAXED, __HIP_MEMORY_SCOPE_AGENT);
}

// ---------------- kernel 3: fused masked-softmax attention + PV + mean ----------------
// 256 blocks = (i-block 128 rows) x head; 8 waves; triple-buffered V, double P,
// counted vmcnt(8) + raw barrier (T4): V prefetch stays in flight across barrier.
#define D_OFF 114688
#define NJT (NN / 32)
__global__ __launch_bounds__(512, 2) void k_flash(const float* __restrict__ adj,
                                                  const unsigned short* __restrict__ vt,
                                                  const float* __restrict__ srcL,
                                                  const float* __restrict__ dstL,
                                                  float* __restrict__ out) {
    __shared__ alignas(16) char smem[115200];  // V 3x32KB | P 2x8KB | denom 512B
    const int tid = threadIdx.x;
    const int w = tid >> 6, lane = tid & 63;
    const int lr = lane & 15, lc = lane >> 4;
    const int h = blockIdx.x & 3;
    const int i0 = (int)(blockIdx.x >> 2) * 128;
    const int ih = w >> 2, dq = w & 3;
    float* denom = (float*)(smem + D_OFF);

    const int srow = i0 + w * 16 + lr;
    const float srcv = srcL[h * NN + srow];
    const float* __restrict__ adjp = adj + (size_t)srow * NN + lc * 8;
    const float* __restrict__ dlp = dstL + h * NN + lc * 8;
    const unsigned short* __restrict__ vth = vt + (size_t)(h * 512) * NN;
    float dsum = 0.f;
    f32x4 acc[4][8] = {};

    // per-lane V-stage source offsets (element units), d/j from paired-row XOR layout
    unsigned voff[4];
#pragma unroll
    for (int it = 0; it < 4; it++) {
        const int o = it * 8192 + w * 1024 + lane * 16;
        const int row = o >> 7;
        const int z = ((o >> 4) & 7) ^ (row & 7);
        const int d = (row << 1) | (z >> 2);
        voff[it] = (unsigned)d * NN + ((z & 3) << 3);
    }
    // P write slot for this lane (row r = w*16+lr, j-chunk lc), paired-row XOR layout
    const int prow = w * 16 + lr;
    const int psl = (((prow & 1) << 2) | lc) ^ ((prow >> 1) & 7);
    const int poff = (prow >> 1) * 128 + (psl << 4);

    char* vc = smem;                 // V buffer holding current tile
    char* vn = smem + 32768;         // being staged (tile+1)
    char* vnn = smem + 65536;        // spare (tile+2 target)
    char* pc = smem + 98304;         // P current
    char* pn = smem + 106496;        // P next

#define STAGE(J0, DST)                                                                   \
    {                                                                                    \
        _Pragma("unroll") for (int it = 0; it < 4; it++)                                 \
            global_to_lds16(vth + voff[it] + (J0), (DST) + it * 8192 + w * 1024);        \
    }

#define LOADROW(J0)                                                                      \
    {                                                                                    \
        aj0 = *(const float4*)(adjp + (J0));                                             \
        aj1 = *(const float4*)(adjp + (J0) + 4);                                         \
        dl0 = *(const float4*)(dlp + (J0));                                              \
        dl1 = *(const float4*)(dlp + (J0) + 4);                                          \
    }

#define SCORE()                                                                          \
    {                                                                                    \
        const float padj[8] = {aj0.x, aj0.y, aj0.z, aj0.w, aj1.x, aj1.y, aj1.z, aj1.w};  \
        const float pdst[8] = {dl0.x, dl0.y, dl0.z, dl0.w, dl1.x, dl1.y, dl1.z, dl1.w};  \
        _Pragma("unroll") for (int q = 0; q < 8; q++) {                                  \
            const float x = srcv + pdst[q];                                              \
            const float l2 = fmaxf(x, 0.01f * x);                                        \
            const float p = exp2f(l2 + padj[q]);                                         \
            dsum += p;                                                                   \
            pfrag[q] = (short)f2bf(p);                                                   \
        }                                                                                \
    }

#define PV(VBUF, PBUF)                                                                   \
    {                                                                                    \
        const char* vb = (VBUF);                                                         \
        const char* pb = (PBUF);                                                         \
        short8 afr[4];                                                                   \
        _Pragma("unroll") for (int t = 0; t < 4; t++) {                                  \
            const int rr = ih * 64 + t * 16 + lr;                                        \
            const int sl = (((rr & 1) << 2) | lc) ^ ((rr >> 1) & 7);                     \
            afr[t] = *(const short8*)(pb + (rr >> 1) * 128 + (sl << 4));                 \
        }                                                                                \
        __builtin_amdgcn_s_setprio(1);                                                   \
        _Pragma("unroll") for (int s = 0; s < 8; s++) {                                  \
            const int d = dq * 128 + s * 16 + lr;                                        \
            const int sl = (((d & 1) << 2) | lc) ^ ((d >> 1) & 7);                       \
            const short8 bfr = *(const short8*)(vb + (d >> 1) * 128 + (sl << 4));        \
            _Pragma("unroll") for (int t = 0; t < 4; t++)                                \
                acc[t][s] = __builtin_amdgcn_mfma_f32_16x16x32_bf16(afr[t], bfr,         \
                                                                    acc[t][s], 0, 0, 0); \
        }                                                                                \
        __builtin_amdgcn_s_setprio(0);                                                   \
    }

    float4 aj0, aj1, dl0, dl1;
    short8 pfrag;
    // ---- prologue: tile 0 (adj regs + V stage + score) ----
    LOADROW(0);
    STAGE(0, vc);
    SCORE();   // compiler auto-waits vmcnt(4) for adj regs; V(0) stays in flight
    *(short8*)(pc + poff) = pfrag;
    // ---- steady state: 1 raw barrier per tile, counted vmcnt ----
#pragma unroll 1
    for (int jb = 0; jb < NJT - 1; jb++) {
        const int J0 = (jb + 1) * 32;
        LOADROW(J0);     // 4 vmem loads (tile jb+1)
        STAGE(J0, vn);   // 4 global_load_lds (tile jb+1)
        // V(jb) drained when <=8 newest (adj+stage of jb+1) remain; P(jb) via lgkmcnt
        asm volatile("s_waitcnt vmcnt(8) lgkmcnt(0)" ::: "memory");
        __builtin_amdgcn_sched_barrier(0);
        __builtin_amdgcn_s_barrier();
        __builtin_amdgcn_sched_barrier(0);
        PV(vc, pc);      // MFMA on tile jb ...
        SCORE();         // ... overlapped with VALU scores of tile jb+1
        *(short8*)(pn + poff) = pfrag;
        char* tv = vc; vc = vn; vn = vnn; vnn = tv;
        char* tp = pc; pc = pn; pn = tp;
    }
    // ---- tail: last tile ----
    asm volatile("s_waitcnt vmcnt(0) lgkmcnt(0)" ::: "memory");
    __builtin_amdgcn_sched_barrier(0);
    __builtin_amdgcn_s_barrier();
    __builtin_amdgcn_sched_barrier(0);
    PV(vc, pc);

    // --- denominators: reduce 4 lane-partials per row ---
    dsum += __shfl_xor(dsum, 16, 64);
    dsum += __shfl_xor(dsum, 32, 64);
    if (lane < 16) denom[w * 16 + lane] = dsum;
    __syncthreads();
    // --- epilogue: out[i][d] += 0.25 * acc / denom ---
#pragma unroll
    for (int t = 0; t < 4; t++) {
        const int rl = ih * 64 + t * 16 + lc * 4;
#pragma unroll
        for (int q = 0; q < 4; q++) {
            const float inv = 0.25f / denom[rl + q];
            float* orow = out + (size_t)(i0 + rl + q) * 512;
#pragma unroll
            for (int s = 0; s < 8; s++) {
                const int d = dq * 128 + s * 16 + lr;
                __hip_atomic_fetch_add(orow + d, acc[t][s][q] * inv,
                                       __ATOMIC_RELAXED, __HIP_MEMORY_SCOPE_AGENT);
            }
        }
    }
}

extern "C" void kernel_launch(void* const* d_in, const int* in_sizes, int n_in,
                              void* d_out, int out_size, void* d_ws, size_t ws_size,
                              hipStream_t stream) {
    const float* h = (const float*)d_in[0];
    const float* adj = (const float*)d_in[1];
    const float* W = (const float*)d_in[2];
    const float* a = (const float*)d_in[3];
    float* out = (float*)d_out;
    char* ws = (char*)d_ws;
    unsigned short* hb = (unsigned short*)ws;                                  // 8 MB
    unsigned short* Wt = (unsigned short*)(ws + 8388608);                      // 2 MB
    unsigned short* vt = (unsigned short*)(ws + 8388608 + 2097152);            // 32 MB
    float* srcL = (float*)(ws + 8388608 + 2097152 + 33554432);                 // 128 KB
    float* dstL = srcL + NH * NN;                                              // 128 KB

    hipMemsetAsync(d_out, 0, (size_t)out_size * sizeof(float), stream);
    hipMemsetAsync(srcL, 0, 2 * NH * NN * sizeof(float), stream);
    k_convert_h<<<2048, 256, 0, stream>>>(h, hb);
    k_transpose_W<<<dim3(64, 16), 256, 0, stream>>>(W, Wt);
    k_gemm<<<dim3(64, 16), 256, 0, stream>>>(Wt, hb, vt);
    k_srcdst<<<dim3(32, NH, 8), 256, 0, stream>>>(vt, a, srcL, dstL);
    k_flash<<<256, 512, 0, stream>>>(adj, vt, srcL, dstL, out);
}